// Round 1
// baseline (117.511 us; speedup 1.0000x reference)
//
#include <hip/hip_runtime.h>

// CrossAttention collapses algebraically:
//   k[b,m,:] and v[b,m,:] are constant over m (age broadcast BEFORE projection)
//   => scores rows are constant => softmax uniform => attended[b,n,:] = v_vec[b,:]
//   => out[b,n,d] = pixel[b,n,d] + age[b,:]·Wv[:,d] + bv[d]
// Q/Wq/bq/Wk/bk do not affect the output.

#define PIXEL_DIM 768
#define AGE_DIM   128
#define BB        8
#define NN        2048

// Kernel 1: v_vec[b,d] = sum_a age[b,a] * Wv[a,d] + bv[d]   (8 x 768 outputs)
__global__ void ca_compute_vvec(const float* __restrict__ age,
                                const float* __restrict__ Wv,
                                const float* __restrict__ bv,
                                float* __restrict__ v_vec) {
    int tid = blockIdx.x * blockDim.x + threadIdx.x;  // 0 .. 8*768-1
    if (tid >= BB * PIXEL_DIM) return;
    int b = tid / PIXEL_DIM;
    int d = tid - b * PIXEL_DIM;
    const float* ab = age + b * AGE_DIM;
    float sum = bv[d];
    #pragma unroll 8
    for (int a = 0; a < AGE_DIM; ++a) {
        // Wv[a,d]: consecutive d across lanes -> coalesced; age[b,a] broadcast
        sum = fmaf(ab[a], Wv[a * PIXEL_DIM + d], sum);
    }
    v_vec[tid] = sum;
}

// Kernel 2: out[b,n,d] = pixel[b,n,d] + v_vec[b,d], float4-vectorized.
// PIXEL_DIM % 4 == 0, so each float4 stays within one row's d-range.
__global__ void ca_add_bcast(const float4* __restrict__ pixel,
                             const float* __restrict__ v_vec,
                             float4* __restrict__ out) {
    const long total4 = (long)BB * NN * PIXEL_DIM / 4;
    long i = (long)blockIdx.x * blockDim.x + threadIdx.x;
    if (i >= total4) return;
    long e = i * 4;
    int d = (int)(e % PIXEL_DIM);                       // multiple of 4
    int b = (int)(e / ((long)NN * PIXEL_DIM));
    float4 p = pixel[i];
    float4 v = *(const float4*)(v_vec + b * PIXEL_DIM + d);  // L2-resident (24 KB)
    float4 r;
    r.x = p.x + v.x;
    r.y = p.y + v.y;
    r.z = p.z + v.z;
    r.w = p.w + v.w;
    out[i] = r;
}

extern "C" void kernel_launch(void* const* d_in, const int* in_sizes, int n_in,
                              void* d_out, int out_size, void* d_ws, size_t ws_size,
                              hipStream_t stream) {
    const float* pixel = (const float*)d_in[0];  // [8, 2048, 768]
    const float* age   = (const float*)d_in[1];  // [8, 128]
    // d_in[2..5] = Wq, bq, Wk, bk  -- unused (see header comment)
    const float* Wv    = (const float*)d_in[6];  // [128, 768]
    const float* bv    = (const float*)d_in[7];  // [768]
    float* out   = (float*)d_out;
    float* v_vec = (float*)d_ws;                 // 8*768 floats = 24 KB

    {
        int threads = 256;
        int total = BB * PIXEL_DIM;              // 6144
        int blocks = (total + threads - 1) / threads;
        ca_compute_vvec<<<blocks, threads, 0, stream>>>(age, Wv, bv, v_vec);
    }
    {
        int threads = 256;
        long total4 = (long)BB * NN * PIXEL_DIM / 4;  // 3,145,728
        int blocks = (int)((total4 + threads - 1) / threads);
        ca_add_bcast<<<blocks, threads, 0, stream>>>((const float4*)pixel, v_vec,
                                                     (float4*)out);
    }
}